// Round 1
// baseline (981.584 us; speedup 1.0000x reference)
//
#include <hip/hip_runtime.h>

#define NNODES 50000
#define NEDGES 1600000
#define NF 128
#define NC 40
#define NLAYERS 3

// ---------------------------------------------------------------------------
// CSR build: histogram -> scan (3 kernels) -> scatter
// ---------------------------------------------------------------------------

__global__ __launch_bounds__(256) void hist_kernel(const int* __restrict__ dst,
                                                   int* __restrict__ counts) {
    int e = blockIdx.x * 256 + threadIdx.x;
    if (e < NEDGES) atomicAdd(&counts[dst[e]], 1);
}

__global__ __launch_bounds__(1024) void scan1_kernel(const int* __restrict__ counts,
                                                     int* __restrict__ row_ptr,
                                                     int* __restrict__ blk_sums) {
    __shared__ int s[1024];
    int t = threadIdx.x;
    int i = blockIdx.x * 1024 + t;
    int v = (i < NNODES) ? counts[i] : 0;
    s[t] = v;
    __syncthreads();
    for (int off = 1; off < 1024; off <<= 1) {
        int x = (t >= off) ? s[t - off] : 0;
        __syncthreads();
        s[t] += x;
        __syncthreads();
    }
    int incl = s[t];
    if (i < NNODES) row_ptr[i] = incl - v;  // exclusive (block-local)
    if (t == 1023) blk_sums[blockIdx.x] = incl;
}

__global__ void scan2_kernel(int* __restrict__ blk_sums, int nb) {
    if (threadIdx.x == 0 && blockIdx.x == 0) {
        int run = 0;
        for (int b = 0; b < nb; ++b) { int tv = blk_sums[b]; blk_sums[b] = run; run += tv; }
    }
}

__global__ __launch_bounds__(1024) void scan3_kernel(int* __restrict__ row_ptr,
                                                     int* __restrict__ cursor,
                                                     const int* __restrict__ blk_sums) {
    int i = blockIdx.x * 1024 + threadIdx.x;
    if (i < NNODES) {
        int v = row_ptr[i] + blk_sums[blockIdx.x];
        row_ptr[i] = v;
        cursor[i] = v;
    }
    if (i == 0) row_ptr[NNODES] = NEDGES;
}

__global__ __launch_bounds__(256) void scatter_kernel(const int* __restrict__ src,
                                                      const int* __restrict__ dst,
                                                      const float* __restrict__ w,
                                                      int* __restrict__ cursor,
                                                      int* __restrict__ src_s,
                                                      float* __restrict__ w_s) {
    int e = blockIdx.x * 256 + threadIdx.x;
    if (e < NEDGES) {
        int d = dst[e];
        int p = atomicAdd(&cursor[d], 1);
        src_s[p] = src[e];
        w_s[p]   = w[e];
    }
}

// ---------------------------------------------------------------------------
// SpMM: one wave per destination node, lane owns 2 features (float2).
// agg[n][:] = sum_e w_e * feat[src_e][:]
// ---------------------------------------------------------------------------

__global__ __launch_bounds__(256) void spmm_kernel(const int* __restrict__ row_ptr,
                                                   const int* __restrict__ src_s,
                                                   const float* __restrict__ w_s,
                                                   const float* __restrict__ feat,
                                                   float* __restrict__ agg) {
    int wave = threadIdx.x >> 6;
    int lane = threadIdx.x & 63;
    int n = blockIdx.x * 4 + wave;

    int e0 = __builtin_amdgcn_readfirstlane(row_ptr[n]);
    int e1 = __builtin_amdgcn_readfirstlane(row_ptr[n + 1]);

    const float2* f2 = (const float2*)feat;
    float2 acc; acc.x = 0.f; acc.y = 0.f;

    int e = e0;
    for (; e + 1 < e1; e += 2) {
        int s0 = src_s[e];
        int s1 = src_s[e + 1];
        float w0 = w_s[e];
        float w1 = w_s[e + 1];
        float2 v0 = f2[(size_t)s0 * 64 + lane];
        float2 v1 = f2[(size_t)s1 * 64 + lane];
        acc.x += w0 * v0.x + w1 * v1.x;
        acc.y += w0 * v0.y + w1 * v1.y;
    }
    if (e < e1) {
        int s0 = src_s[e];
        float w0 = w_s[e];
        float2 v0 = f2[(size_t)s0 * 64 + lane];
        acc.x += w0 * v0.x;
        acc.y += w0 * v0.y;
    }
    ((float2*)agg)[(size_t)n * 64 + lane] = acc;
}

// ---------------------------------------------------------------------------
// Dense GEMM: out[N,NJ] = A[N,128] @ W[128,NJ] + bias (+relu) (+res)
// Block: 256 threads. Thread computes RPT rows x JW cols.
// W and A-tile staged in LDS (A padded stride to avoid bank conflicts).
// ---------------------------------------------------------------------------

template <int NJ, int JW, int RPT, bool RELU, bool RES>
__global__ __launch_bounds__(256) void gemm_kernel(const float* __restrict__ A,
                                                   const float* __restrict__ W,
                                                   const float* __restrict__ bias,
                                                   const float* __restrict__ res,
                                                   float* __restrict__ out) {
    constexpr int TPR = NJ / JW;              // threads per row
    constexpr int RPB = (256 / TPR) * RPT;    // rows per block
    constexpr int LDA = NF + 4;               // padded LDS row stride (floats)

    __shared__ float lW[NF * NJ];
    __shared__ float lA[RPB * LDA];

    int t = threadIdx.x;
    int row0blk = blockIdx.x * RPB;

    // stage W
    for (int idx = t * 4; idx < NF * NJ; idx += 256 * 4) {
        *(float4*)&lW[idx] = *(const float4*)&W[idx];
    }
    // stage A tile (zero-pad OOB rows)
    for (int idx = t * 4; idx < RPB * NF; idx += 256 * 4) {
        int r = idx / NF, k = idx % NF;
        int grow = row0blk + r;
        float4 v; v.x = 0.f; v.y = 0.f; v.z = 0.f; v.w = 0.f;
        if (grow < NNODES) v = *(const float4*)&A[(size_t)grow * NF + k];
        *(float4*)&lA[r * LDA + k] = v;
    }
    __syncthreads();

    int jt = t % TPR;
    int rg = t / TPR;
    int j0 = jt * JW;
    int r0 = rg * RPT;

    float acc[RPT][JW];
#pragma unroll
    for (int r = 0; r < RPT; ++r)
#pragma unroll
        for (int j = 0; j < JW; ++j) acc[r][j] = 0.f;

    for (int k = 0; k < NF; ++k) {
        float wv[JW];
#pragma unroll
        for (int j = 0; j < JW; ++j) wv[j] = lW[k * NJ + j0 + j];
#pragma unroll
        for (int r = 0; r < RPT; ++r) {
            float a = lA[(r0 + r) * LDA + k];
#pragma unroll
            for (int j = 0; j < JW; ++j) acc[r][j] += a * wv[j];
        }
    }

#pragma unroll
    for (int r = 0; r < RPT; ++r) {
        int grow = row0blk + r0 + r;
        if (grow < NNODES) {
#pragma unroll
            for (int j = 0; j < JW; ++j) {
                float v = acc[r][j] + bias[j0 + j];
                if (RELU) v = fmaxf(v, 0.f);
                if (RES) v += res[(size_t)grow * NF + j0 + j];
                out[(size_t)grow * NJ + j0 + j] = v;
            }
        }
    }
}

// ---------------------------------------------------------------------------

extern "C" void kernel_launch(void* const* d_in, const int* in_sizes, int n_in,
                              void* d_out, int out_size, void* d_ws, size_t ws_size,
                              hipStream_t stream) {
    const float* x    = (const float*)d_in[0];
    const int*   esrc = (const int*)d_in[1];
    const int*   edst = (const int*)d_in[2];
    const float* ew   = (const float*)d_in[3];
    const float* W0   = (const float*)d_in[4];
    const float* b0   = (const float*)d_in[5];
    const float* Ws   = (const float*)d_in[6];
    const float* bs   = (const float*)d_in[7];
    const float* Wout = (const float*)d_in[8];
    const float* bout = (const float*)d_in[9];
    float* out = (float*)d_out;

    // workspace carve (256-B aligned)
    char* p = (char*)d_ws;
    auto alloc = [&](size_t bytes) -> void* {
        void* r = (void*)p;
        p += (bytes + 255) & ~(size_t)255;
        return r;
    };
    int*   counts   = (int*)alloc((size_t)NNODES * 4);        // reused as cursor
    int*   row_ptr  = (int*)alloc((size_t)(NNODES + 1) * 4);
    int*   blk_sums = (int*)alloc(64 * 4);
    int*   src_s    = (int*)alloc((size_t)NEDGES * 4);
    float* w_s      = (float*)alloc((size_t)NEDGES * 4);
    float* agg      = (float*)alloc((size_t)NNODES * NF * 4);
    float* h0       = (float*)alloc((size_t)NNODES * NF * 4);
    float* h1       = (float*)alloc((size_t)NNODES * NF * 4);

    const int nb_scan = (NNODES + 1023) / 1024;  // 49

    // ---- CSR build ----
    hipMemsetAsync(counts, 0, (size_t)NNODES * 4, stream);
    hist_kernel<<<NEDGES / 256, 256, 0, stream>>>(edst, counts);
    scan1_kernel<<<nb_scan, 1024, 0, stream>>>(counts, row_ptr, blk_sums);
    scan2_kernel<<<1, 64, 0, stream>>>(blk_sums, nb_scan);
    scan3_kernel<<<nb_scan, 1024, 0, stream>>>(row_ptr, counts, blk_sums);
    scatter_kernel<<<NEDGES / 256, 256, 0, stream>>>(esrc, edst, ew, counts, src_s, w_s);

    // ---- layer 0: h0 = relu(spmm(x) @ W0 + b0) ----
    spmm_kernel<<<NNODES / 4, 256, 0, stream>>>(row_ptr, src_s, w_s, x, agg);
    gemm_kernel<NF, 8, 4, true, false>
        <<<(NNODES + 63) / 64, 256, 0, stream>>>(agg, W0, b0, nullptr, h0);

    // ---- residual layers ----
    float* hin = h0;
    float* hout = h1;
    for (int l = 0; l < NLAYERS; ++l) {
        spmm_kernel<<<NNODES / 4, 256, 0, stream>>>(row_ptr, src_s, w_s, hin, agg);
        gemm_kernel<NF, 8, 4, true, true>
            <<<(NNODES + 63) / 64, 256, 0, stream>>>(agg, Ws + (size_t)l * NF * NF,
                                                     bs + (size_t)l * NF, hin, hout);
        float* tmp = hin; hin = hout; hout = tmp;
    }

    // ---- output head: out = hin @ Wout + bout ----
    gemm_kernel<NC, 5, 4, false, false>
        <<<(NNODES + 127) / 128, 256, 0, stream>>>(hin, Wout, bout, nullptr, out);
}

// Round 2
// 665.866 us; speedup vs baseline: 1.4741x; 1.4741x over previous
//
#include <hip/hip_runtime.h>
#include <hip/hip_bf16.h>

#define NNODES 50000
#define NEDGES 1600000
#define NF 128
#define NC 40
#define NLAYERS 3

// ---------------------------------------------------------------------------
// CSR build: histogram -> scan (3 kernels) -> scatter (packed int2)
// ---------------------------------------------------------------------------

__global__ __launch_bounds__(256) void hist_kernel(const int* __restrict__ dst,
                                                   int* __restrict__ counts) {
    int e = blockIdx.x * 256 + threadIdx.x;
    if (e < NEDGES) atomicAdd(&counts[dst[e]], 1);
}

__global__ __launch_bounds__(1024) void scan1_kernel(const int* __restrict__ counts,
                                                     int* __restrict__ row_ptr,
                                                     int* __restrict__ blk_sums) {
    __shared__ int s[1024];
    int t = threadIdx.x;
    int i = blockIdx.x * 1024 + t;
    int v = (i < NNODES) ? counts[i] : 0;
    s[t] = v;
    __syncthreads();
    for (int off = 1; off < 1024; off <<= 1) {
        int x = (t >= off) ? s[t - off] : 0;
        __syncthreads();
        s[t] += x;
        __syncthreads();
    }
    int incl = s[t];
    if (i < NNODES) row_ptr[i] = incl - v;  // exclusive (block-local)
    if (t == 1023) blk_sums[blockIdx.x] = incl;
}

__global__ void scan2_kernel(int* __restrict__ blk_sums, int nb) {
    if (threadIdx.x == 0 && blockIdx.x == 0) {
        int run = 0;
        for (int b = 0; b < nb; ++b) { int tv = blk_sums[b]; blk_sums[b] = run; run += tv; }
    }
}

__global__ __launch_bounds__(1024) void scan3_kernel(int* __restrict__ row_ptr,
                                                     int* __restrict__ cursor,
                                                     const int* __restrict__ blk_sums) {
    int i = blockIdx.x * 1024 + threadIdx.x;
    if (i < NNODES) {
        int v = row_ptr[i] + blk_sums[blockIdx.x];
        row_ptr[i] = v;
        cursor[i] = v;
    }
    if (i == 0) row_ptr[NNODES] = NEDGES;
}

__global__ __launch_bounds__(256) void scatter_kernel(const int* __restrict__ src,
                                                      const int* __restrict__ dst,
                                                      const float* __restrict__ w,
                                                      int* __restrict__ cursor,
                                                      int2* __restrict__ edges) {
    int e = blockIdx.x * 256 + threadIdx.x;
    if (e < NEDGES) {
        int d = dst[e];
        int p = atomicAdd(&cursor[d], 1);
        int2 v;
        v.x = src[e];
        v.y = __float_as_int(w[e]);
        edges[p] = v;
    }
}

// ---------------------------------------------------------------------------
// fp32 -> bf16 feature-table convert (x only; later tables come from GEMM)
// ---------------------------------------------------------------------------

__global__ __launch_bounds__(256) void cvt_kernel(const float2* __restrict__ in,
                                                  __hip_bfloat162* __restrict__ out,
                                                  int n2) {
    int i = blockIdx.x * 256 + threadIdx.x;
    int stride = gridDim.x * 256;
    for (; i < n2; i += stride) {
        float2 v = in[i];
        __hip_bfloat162 b;
        b.x = __float2bfloat16(v.x);
        b.y = __float2bfloat16(v.y);
        out[i] = b;
    }
}

// ---------------------------------------------------------------------------
// SpMM: one wave per destination node, lane owns 2 features (bf16x2 gather,
// fp32 accumulate). agg[n][:] = sum_e w_e * feat[src_e][:]
// ---------------------------------------------------------------------------

__global__ __launch_bounds__(256) void spmm_kernel(const int* __restrict__ row_ptr,
                                                   const int2* __restrict__ edges,
                                                   const __hip_bfloat162* __restrict__ feat,
                                                   float2* __restrict__ agg) {
    int wave = threadIdx.x >> 6;
    int lane = threadIdx.x & 63;
    int n = blockIdx.x * 4 + wave;

    int e0 = __builtin_amdgcn_readfirstlane(row_ptr[n]);
    int e1 = __builtin_amdgcn_readfirstlane(row_ptr[n + 1]);

    float2 acc;
    acc.x = 0.f;
    acc.y = 0.f;

    int e = e0;
    for (; e + 3 < e1; e += 4) {
        int2 d0 = edges[e];
        int2 d1 = edges[e + 1];
        int2 d2 = edges[e + 2];
        int2 d3 = edges[e + 3];
        __hip_bfloat162 v0 = feat[(size_t)d0.x * 64 + lane];
        __hip_bfloat162 v1 = feat[(size_t)d1.x * 64 + lane];
        __hip_bfloat162 v2 = feat[(size_t)d2.x * 64 + lane];
        __hip_bfloat162 v3 = feat[(size_t)d3.x * 64 + lane];
        float w0 = __int_as_float(d0.y);
        float w1 = __int_as_float(d1.y);
        float w2 = __int_as_float(d2.y);
        float w3 = __int_as_float(d3.y);
        acc.x += w0 * __bfloat162float(v0.x) + w1 * __bfloat162float(v1.x);
        acc.y += w0 * __bfloat162float(v0.y) + w1 * __bfloat162float(v1.y);
        acc.x += w2 * __bfloat162float(v2.x) + w3 * __bfloat162float(v3.x);
        acc.y += w2 * __bfloat162float(v2.y) + w3 * __bfloat162float(v3.y);
    }
    for (; e < e1; ++e) {
        int2 d0 = edges[e];
        __hip_bfloat162 v0 = feat[(size_t)d0.x * 64 + lane];
        float w0 = __int_as_float(d0.y);
        acc.x += w0 * __bfloat162float(v0.x);
        acc.y += w0 * __bfloat162float(v0.y);
    }
    agg[(size_t)n * 64 + lane] = acc;
}

// ---------------------------------------------------------------------------
// GEMM 128x128: out[g][:] = relu(A[g][:] @ W + b) (+ out[g][:] in-place res),
// optional bf16 copy for the next SpMM gather table.
// 512 threads, 128-row x 128-col tile, LDS = 130 KB -> 8 waves/CU.
// Thread computes 4 rows x (two float4 col chunks at c0 and 64+c0).
// ---------------------------------------------------------------------------

template <bool RES, bool WB16>
__global__ __launch_bounds__(512) void gemm128_kernel(const float* __restrict__ A,
                                                      const float* __restrict__ W,
                                                      const float* __restrict__ bias,
                                                      float* out,
                                                      __hip_bfloat162* __restrict__ outb) {
    constexpr int LDA = NF + 4;  // 132 floats, padded
    __shared__ float lW[NF * NF];
    __shared__ float lA[128 * LDA];

    int t = threadIdx.x;
    int row0blk = blockIdx.x * 128;

    for (int idx = t * 4; idx < NF * NF; idx += 512 * 4) {
        *(float4*)&lW[idx] = *(const float4*)&W[idx];
    }
    for (int idx = t * 4; idx < 128 * NF; idx += 512 * 4) {
        int r = idx >> 7;
        int k = idx & 127;
        int g = row0blk + r;
        float4 v;
        v.x = 0.f; v.y = 0.f; v.z = 0.f; v.w = 0.f;
        if (g < NNODES) v = *(const float4*)&A[(size_t)g * NF + k];
        *(float4*)&lA[r * LDA + k] = v;
    }
    __syncthreads();

    int m = t & 15;      // col group: cols m*4..m*4+3 and 64+m*4..64+m*4+3
    int rg = t >> 4;     // 0..31
    int r0 = rg * 4;
    int c0 = m * 4;

    float acc[4][8];
#pragma unroll
    for (int r = 0; r < 4; ++r)
#pragma unroll
        for (int j = 0; j < 8; ++j) acc[r][j] = 0.f;

#pragma unroll 4
    for (int k = 0; k < NF; ++k) {
        float4 w0 = *(float4*)&lW[k * NF + c0];
        float4 w1 = *(float4*)&lW[k * NF + 64 + c0];
#pragma unroll
        for (int r = 0; r < 4; ++r) {
            float a = lA[(r0 + r) * LDA + k];
            acc[r][0] += a * w0.x;
            acc[r][1] += a * w0.y;
            acc[r][2] += a * w0.z;
            acc[r][3] += a * w0.w;
            acc[r][4] += a * w1.x;
            acc[r][5] += a * w1.y;
            acc[r][6] += a * w1.z;
            acc[r][7] += a * w1.w;
        }
    }

    float4 bv0 = *(const float4*)&bias[c0];
    float4 bv1 = *(const float4*)&bias[64 + c0];

#pragma unroll
    for (int r = 0; r < 4; ++r) {
        int g = row0blk + r0 + r;
        if (g < NNODES) {
            float4 v0, v1;
            v0.x = fmaxf(acc[r][0] + bv0.x, 0.f);
            v0.y = fmaxf(acc[r][1] + bv0.y, 0.f);
            v0.z = fmaxf(acc[r][2] + bv0.z, 0.f);
            v0.w = fmaxf(acc[r][3] + bv0.w, 0.f);
            v1.x = fmaxf(acc[r][4] + bv1.x, 0.f);
            v1.y = fmaxf(acc[r][5] + bv1.y, 0.f);
            v1.z = fmaxf(acc[r][6] + bv1.z, 0.f);
            v1.w = fmaxf(acc[r][7] + bv1.w, 0.f);
            if (RES) {
                // in-place residual: read-before-write, same element, same thread
                float4 o0 = *(const float4*)&out[(size_t)g * NF + c0];
                float4 o1 = *(const float4*)&out[(size_t)g * NF + 64 + c0];
                v0.x += o0.x; v0.y += o0.y; v0.z += o0.z; v0.w += o0.w;
                v1.x += o1.x; v1.y += o1.y; v1.z += o1.z; v1.w += o1.w;
            }
            *(float4*)&out[(size_t)g * NF + c0] = v0;
            *(float4*)&out[(size_t)g * NF + 64 + c0] = v1;
            if (WB16) {
                __hip_bfloat162 p0, p1, p2, p3;
                p0.x = __float2bfloat16(v0.x); p0.y = __float2bfloat16(v0.y);
                p1.x = __float2bfloat16(v0.z); p1.y = __float2bfloat16(v0.w);
                p2.x = __float2bfloat16(v1.x); p2.y = __float2bfloat16(v1.y);
                p3.x = __float2bfloat16(v1.z); p3.y = __float2bfloat16(v1.w);
                size_t base = (size_t)g * 64;
                outb[base + m * 2]      = p0;
                outb[base + m * 2 + 1]  = p1;
                outb[base + 32 + m * 2] = p2;
                outb[base + 33 + m * 2] = p3;
            }
        }
    }
}

// ---------------------------------------------------------------------------
// Head GEMM: out[N,40] = A[N,128] @ Wout + bout. 256 threads, lW-only LDS
// (20.5 KB -> full occupancy). Thread: 4 rows x 5 cols; A via L1-broadcast
// global reads (8 threads share each row).
// ---------------------------------------------------------------------------

__global__ __launch_bounds__(256) void head_kernel(const float* __restrict__ A,
                                                   const float* __restrict__ W,
                                                   const float* __restrict__ bias,
                                                   float* __restrict__ out) {
    __shared__ float lW[NF * NC];  // [k][j]
    int t = threadIdx.x;
    for (int idx = t * 4; idx < NF * NC; idx += 256 * 4) {
        *(float4*)&lW[idx] = *(const float4*)&W[idx];
    }
    __syncthreads();

    int m = t & 7;    // col group: cols m*5..m*5+4
    int rg = t >> 3;  // 0..31
    int row0 = blockIdx.x * 128 + rg * 4;

    float acc[4][5];
#pragma unroll
    for (int r = 0; r < 4; ++r)
#pragma unroll
        for (int j = 0; j < 5; ++j) acc[r][j] = 0.f;

    // clamp row indices for loads; stores are guarded
    int gr[4];
#pragma unroll
    for (int r = 0; r < 4; ++r) {
        int g = row0 + r;
        gr[r] = g < NNODES ? g : NNODES - 1;
    }

    for (int k = 0; k < NF; k += 4) {
        float4 a4[4];
#pragma unroll
        for (int r = 0; r < 4; ++r)
            a4[r] = *(const float4*)&A[(size_t)gr[r] * NF + k];
#pragma unroll
        for (int kk = 0; kk < 4; ++kk) {
            float wv[5];
#pragma unroll
            for (int j = 0; j < 5; ++j) wv[j] = lW[(k + kk) * NC + m * 5 + j];
#pragma unroll
            for (int r = 0; r < 4; ++r) {
                float a = (kk == 0) ? a4[r].x : (kk == 1) ? a4[r].y : (kk == 2) ? a4[r].z : a4[r].w;
#pragma unroll
                for (int j = 0; j < 5; ++j) acc[r][j] += a * wv[j];
            }
        }
    }

#pragma unroll
    for (int r = 0; r < 4; ++r) {
        int g = row0 + r;
        if (g < NNODES) {
#pragma unroll
            for (int j = 0; j < 5; ++j) {
                out[(size_t)g * NC + m * 5 + j] = acc[r][j] + bias[m * 5 + j];
            }
        }
    }
}

// ---------------------------------------------------------------------------

extern "C" void kernel_launch(void* const* d_in, const int* in_sizes, int n_in,
                              void* d_out, int out_size, void* d_ws, size_t ws_size,
                              hipStream_t stream) {
    const float* x    = (const float*)d_in[0];
    const int*   esrc = (const int*)d_in[1];
    const int*   edst = (const int*)d_in[2];
    const float* ew   = (const float*)d_in[3];
    const float* W0   = (const float*)d_in[4];
    const float* b0   = (const float*)d_in[5];
    const float* Ws   = (const float*)d_in[6];
    const float* bs   = (const float*)d_in[7];
    const float* Wout = (const float*)d_in[8];
    const float* bout = (const float*)d_in[9];
    float* out = (float*)d_out;

    // workspace carve (256-B aligned); total ~77 MB
    char* p = (char*)d_ws;
    auto alloc = [&](size_t bytes) -> void* {
        void* r = (void*)p;
        p += (bytes + 255) & ~(size_t)255;
        return r;
    };
    int*   counts   = (int*)alloc((size_t)NNODES * 4);        // reused as cursor
    int*   row_ptr  = (int*)alloc((size_t)(NNODES + 1) * 4);
    int*   blk_sums = (int*)alloc(64 * 4);
    int2*  edges    = (int2*)alloc((size_t)NEDGES * 8);
    float* agg      = (float*)alloc((size_t)NNODES * NF * 4);
    float* h        = (float*)alloc((size_t)NNODES * NF * 4);
    __hip_bfloat162* hb = (__hip_bfloat162*)alloc((size_t)NNODES * NF * 2);

    const int nb_scan = (NNODES + 1023) / 1024;  // 49
    const int gemm_grid = (NNODES + 127) / 128;  // 391

    // ---- CSR build ----
    hipMemsetAsync(counts, 0, (size_t)NNODES * 4, stream);
    hist_kernel<<<NEDGES / 256, 256, 0, stream>>>(edst, counts);
    scan1_kernel<<<nb_scan, 1024, 0, stream>>>(counts, row_ptr, blk_sums);
    scan2_kernel<<<1, 64, 0, stream>>>(blk_sums, nb_scan);
    scan3_kernel<<<nb_scan, 1024, 0, stream>>>(row_ptr, counts, blk_sums);
    scatter_kernel<<<NEDGES / 256, 256, 0, stream>>>(esrc, edst, ew, counts, edges);

    // ---- x -> bf16 table ----
    cvt_kernel<<<2048, 256, 0, stream>>>((const float2*)x, hb, NNODES * 64);

    // ---- layer 0: h = relu(spmm(xb) @ W0 + b0); emit bf16 copy ----
    spmm_kernel<<<NNODES / 4, 256, 0, stream>>>(row_ptr, edges, hb, (float2*)agg);
    gemm128_kernel<false, true>
        <<<gemm_grid, 512, 0, stream>>>(agg, W0, b0, h, hb);

    // ---- residual layers (in-place residual on h) ----
    for (int l = 0; l < NLAYERS; ++l) {
        spmm_kernel<<<NNODES / 4, 256, 0, stream>>>(row_ptr, edges, hb, (float2*)agg);
        if (l < NLAYERS - 1) {
            gemm128_kernel<true, true>
                <<<gemm_grid, 512, 0, stream>>>(agg, Ws + (size_t)l * NF * NF,
                                                bs + (size_t)l * NF, h, hb);
        } else {
            gemm128_kernel<true, false>
                <<<gemm_grid, 512, 0, stream>>>(agg, Ws + (size_t)l * NF * NF,
                                                bs + (size_t)l * NF, h, nullptr);
        }
    }

    // ---- output head ----
    head_kernel<<<gemm_grid, 256, 0, stream>>>(h, Wout, bout, out);
}